// Round 3
// baseline (490.802 us; speedup 1.0000x reference)
//
#include <hip/hip_runtime.h>
#include <hip/hip_bf16.h>
#include <stdint.h>

#define D_MODEL 1024
#define NHEAD   16
#define HDIM    64
#define SEQ     2048
#define BH      64   // 4 batches * 16 heads

typedef short bf16x8 __attribute__((ext_vector_type(8)));
typedef float f32x4  __attribute__((ext_vector_type(4)));

static __device__ __forceinline__ float bf2f(ushort u) {
    union { uint32_t i; float f; } v; v.i = ((uint32_t)u) << 16; return v.f;
}
static __device__ __forceinline__ ushort f2bf(float f) {
    __hip_bfloat16 h = __float2bfloat16(f);
    union { __hip_bfloat16 h; ushort u; } v; v.h = h; return v.u;
}
// Load 8 fp32, convert to bf16 (RNE), store 16B to LDS.
static __device__ __forceinline__ void cvt_store8(ushort* dst, const float* src) {
    float4 a = *(const float4*)src;
    float4 b = *(const float4*)(src + 4);
    uint4 o;
    o.x = (uint32_t)f2bf(a.x) | ((uint32_t)f2bf(a.y) << 16);
    o.y = (uint32_t)f2bf(a.z) | ((uint32_t)f2bf(a.w) << 16);
    o.z = (uint32_t)f2bf(b.x) | ((uint32_t)f2bf(b.y) << 16);
    o.w = (uint32_t)f2bf(b.z) | ((uint32_t)f2bf(b.w) << 16);
    *(uint4*)dst = o;
}

// ---------------------------------------------------------------------------
// GEMM1: qkv = X[8192,1024](f32) * Wqkv[3072,1024](f32)^T, bf16 MFMA compute.
// Scatter epilogue: q,k -> [bh][s][d] bf16 ; v -> transposed [bh][d][s] bf16.
// ---------------------------------------------------------------------------
__global__ __launch_bounds__(256)
void gemm_qkv(const float* __restrict__ X, const float* __restrict__ W,
              ushort* __restrict__ qb, ushort* __restrict__ kb,
              ushort* __restrict__ vt)
{
    __shared__ ushort As[128 * 72];
    __shared__ ushort Bs[128 * 72];
    const int K = 1024;
    const int m0 = blockIdx.y * 128;
    const int n0 = blockIdx.x * 128;
    const int t = threadIdx.x;
    const int lane = t & 63, wv = t >> 6;
    const int wm = (wv >> 1) * 64, wn = (wv & 1) * 64;
    const int l15 = lane & 15, quad = lane >> 4;

    f32x4 acc[4][4];
#pragma unroll
    for (int i = 0; i < 4; i++)
#pragma unroll
        for (int j = 0; j < 4; j++) acc[i][j] = (f32x4){0.f, 0.f, 0.f, 0.f};

    for (int k0 = 0; k0 < K; k0 += 64) {
        __syncthreads();
#pragma unroll
        for (int i = 0; i < 4; i++) {
            int slot = t + 256 * i;
            int r = slot >> 3, c = (slot & 7) * 8;
            cvt_store8(&As[r * 72 + c], &X[(size_t)(m0 + r) * K + k0 + c]);
            cvt_store8(&Bs[r * 72 + c], &W[(size_t)(n0 + r) * K + k0 + c]);
        }
        __syncthreads();
#pragma unroll
        for (int ks = 0; ks < 2; ks++) {
            bf16x8 af[4], bfr[4];
            const int kc = ks * 32 + quad * 8;
#pragma unroll
            for (int mi = 0; mi < 4; mi++)
                af[mi] = *(const bf16x8*)&As[(wm + mi * 16 + l15) * 72 + kc];
#pragma unroll
            for (int ni = 0; ni < 4; ni++)
                bfr[ni] = *(const bf16x8*)&Bs[(wn + ni * 16 + l15) * 72 + kc];
#pragma unroll
            for (int ni = 0; ni < 4; ni++)
#pragma unroll
                for (int mi = 0; mi < 4; mi++)
                    acc[mi][ni] = __builtin_amdgcn_mfma_f32_16x16x32_bf16(
                        af[mi], bfr[ni], acc[mi][ni], 0, 0, 0);
        }
    }

#pragma unroll
    for (int ni = 0; ni < 4; ni++) {
        const int e = n0 + wn + ni * 16 + l15;
        const int which = e >> 10;
        const int h = (e >> 6) & 15;
        const int d = e & 63;
#pragma unroll
        for (int mi = 0; mi < 4; mi++) {
            const int gm0 = m0 + wm + mi * 16 + quad * 4;
            const int b = gm0 >> 11;
            const int s0 = gm0 & 2047;
            const int bh = b * NHEAD + h;
            if (which == 2) {
                ushort4 pk;
                pk.x = f2bf(acc[mi][ni][0]); pk.y = f2bf(acc[mi][ni][1]);
                pk.z = f2bf(acc[mi][ni][2]); pk.w = f2bf(acc[mi][ni][3]);
                *(ushort4*)&vt[((size_t)bh * HDIM + d) * SEQ + s0] = pk;
            } else {
                ushort* dst = (which == 0) ? qb : kb;
#pragma unroll
                for (int r = 0; r < 4; r++)
                    dst[((size_t)bh * SEQ + s0 + r) * HDIM + d] = f2bf(acc[mi][ni][r]);
            }
        }
    }
}

// ---------------------------------------------------------------------------
// GEMM2: out(f32) = A[8192,1024](bf16) * Wout[1024,1024](f32)^T
// ---------------------------------------------------------------------------
__global__ __launch_bounds__(256)
void gemm_out(const ushort* __restrict__ A, const float* __restrict__ W,
              float* __restrict__ out)
{
    __shared__ ushort As[128 * 72];
    __shared__ ushort Bs[128 * 72];
    const int K = 1024;
    const int m0 = blockIdx.y * 128;
    const int n0 = blockIdx.x * 128;
    const int t = threadIdx.x;
    const int lane = t & 63, wv = t >> 6;
    const int wm = (wv >> 1) * 64, wn = (wv & 1) * 64;
    const int l15 = lane & 15, quad = lane >> 4;

    f32x4 acc[4][4];
#pragma unroll
    for (int i = 0; i < 4; i++)
#pragma unroll
        for (int j = 0; j < 4; j++) acc[i][j] = (f32x4){0.f, 0.f, 0.f, 0.f};

    for (int k0 = 0; k0 < K; k0 += 64) {
        __syncthreads();
#pragma unroll
        for (int i = 0; i < 4; i++) {
            int slot = t + 256 * i;
            int r = slot >> 3, c = (slot & 7) * 8;
            *(uint4*)&As[r * 72 + c] = *(const uint4*)&A[(size_t)(m0 + r) * K + k0 + c];
            cvt_store8(&Bs[r * 72 + c], &W[(size_t)(n0 + r) * K + k0 + c]);
        }
        __syncthreads();
#pragma unroll
        for (int ks = 0; ks < 2; ks++) {
            bf16x8 af[4], bfr[4];
            const int kc = ks * 32 + quad * 8;
#pragma unroll
            for (int mi = 0; mi < 4; mi++)
                af[mi] = *(const bf16x8*)&As[(wm + mi * 16 + l15) * 72 + kc];
#pragma unroll
            for (int ni = 0; ni < 4; ni++)
                bfr[ni] = *(const bf16x8*)&Bs[(wn + ni * 16 + l15) * 72 + kc];
#pragma unroll
            for (int ni = 0; ni < 4; ni++)
#pragma unroll
                for (int mi = 0; mi < 4; mi++)
                    acc[mi][ni] = __builtin_amdgcn_mfma_f32_16x16x32_bf16(
                        af[mi], bfr[ni], acc[mi][ni], 0, 0, 0);
        }
    }

#pragma unroll
    for (int ni = 0; ni < 4; ni++) {
        const int n = n0 + wn + ni * 16 + l15;
#pragma unroll
        for (int mi = 0; mi < 4; mi++) {
            const int gm0 = m0 + wm + mi * 16 + quad * 4;
#pragma unroll
            for (int r = 0; r < 4; r++)
                out[(size_t)(gm0 + r) * 1024 + n] = acc[mi][ni][r];
        }
    }
}

// ---------------------------------------------------------------------------
// RoPE in-place on bf16 q and k buffers, layout [bh][s][64]. One thread/pair.
// ---------------------------------------------------------------------------
__global__ __launch_bounds__(256)
void rope_k(ushort* __restrict__ qb, ushort* __restrict__ kb)
{
    const int idx = blockIdx.x * blockDim.x + threadIdx.x;   // BH*SEQ*32 total
    const int i  = idx & 31;
    const int s  = (idx >> 5) & 2047;
    const int bh = idx >> 16;
    ushort* buf = blockIdx.y ? kb : qb;
    const size_t off = ((size_t)bh * SEQ + s) * HDIM + 2 * i;
    uint32_t pair = *(uint32_t*)&buf[off];
    float x1 = bf2f((ushort)(pair & 0xffff));
    float x2 = bf2f((ushort)(pair >> 16));
    float freq = expf(-(float)i * (9.2103403719761836f / 32.0f));  // 10000^(-i/32)
    float ang = (float)s * freq;
    float sn, cs;
    sincosf(ang, &sn, &cs);
    float o1 = x1 * cs - x2 * sn;
    float o2 = x2 * cs + x1 * sn;
    uint32_t op = (uint32_t)f2bf(o1) | ((uint32_t)f2bf(o2) << 16);
    *(uint32_t*)&buf[off] = op;
}

// ---------------------------------------------------------------------------
// Flash attention, causal. Block = 4 waves; wave w owns q rows [w*16,w*16+16)
// of a 64-row q tile. Writes merged-head bf16 output into `ao` [b][s][1024].
// ---------------------------------------------------------------------------
__global__ __launch_bounds__(256)
void attn_k(const ushort* __restrict__ qb, const ushort* __restrict__ kb,
            const ushort* __restrict__ vt, ushort* __restrict__ ao)
{
    __shared__ ushort Qs[64 * 72];
    __shared__ ushort Ks[64 * 72];
    __shared__ ushort Vs[64 * 72];   // V^T tile: row = d, col = k_local
    __shared__ ushort Ps[64 * 72];

    const int qt = blockIdx.x;       // 0..31
    const int bh = blockIdx.y;       // 0..63
    const int q0 = qt * 64;
    const int t = threadIdx.x;
    const int lane = t & 63, wv = t >> 6;
    const int l15 = lane & 15, quad = lane >> 4;

#pragma unroll
    for (int i = 0; i < 2; i++) {
        int slot = t + 256 * i;
        int r = slot >> 3, c = (slot & 7) * 8;
        *(uint4*)&Qs[r * 72 + c] =
            *(const uint4*)&qb[((size_t)bh * SEQ + q0 + r) * HDIM + c];
    }
    __syncthreads();
    bf16x8 qa[2];
#pragma unroll
    for (int ks = 0; ks < 2; ks++)
        qa[ks] = *(const bf16x8*)&Qs[(wv * 16 + l15) * 72 + ks * 32 + quad * 8];

    f32x4 accO[4];
#pragma unroll
    for (int i = 0; i < 4; i++) accO[i] = (f32x4){0.f, 0.f, 0.f, 0.f};
    float mrow[4], lrow[4];
#pragma unroll
    for (int r = 0; r < 4; r++) { mrow[r] = -30000.f; lrow[r] = 0.f; }

    for (int kt = 0; kt <= qt; kt++) {
        const int k0 = kt * 64;
        __syncthreads();
#pragma unroll
        for (int i = 0; i < 2; i++) {
            int slot = t + 256 * i;
            int r = slot >> 3, c = (slot & 7) * 8;
            *(uint4*)&Ks[r * 72 + c] =
                *(const uint4*)&kb[((size_t)bh * SEQ + k0 + r) * HDIM + c];
            *(uint4*)&Vs[r * 72 + c] =
                *(const uint4*)&vt[((size_t)bh * HDIM + r) * SEQ + k0 + c];
        }
        __syncthreads();

        // S = Q K^T
        f32x4 sc[4];
#pragma unroll
        for (int nt = 0; nt < 4; nt++) {
            sc[nt] = (f32x4){0.f, 0.f, 0.f, 0.f};
#pragma unroll
            for (int ks = 0; ks < 2; ks++) {
                bf16x8 bk = *(const bf16x8*)&Ks[(nt * 16 + l15) * 72 + ks * 32 + quad * 8];
                sc[nt] = __builtin_amdgcn_mfma_f32_16x16x32_bf16(qa[ks], bk, sc[nt], 0, 0, 0);
            }
        }

        const bool diag = (kt == qt);
#pragma unroll
        for (int nt = 0; nt < 4; nt++) {
            const int kg = k0 + nt * 16 + l15;
#pragma unroll
            for (int r = 0; r < 4; r++) {
                float v = sc[nt][r] * 0.125f;
                if (diag) {
                    int qg = q0 + wv * 16 + quad * 4 + r;
                    if (kg > qg) v = -30000.f;
                }
                sc[nt][r] = v;
            }
        }

        float mnew[4];
#pragma unroll
        for (int r = 0; r < 4; r++) {
            float m = fmaxf(fmaxf(sc[0][r], sc[1][r]), fmaxf(sc[2][r], sc[3][r]));
            m = fmaxf(m, __shfl_xor(m, 1));
            m = fmaxf(m, __shfl_xor(m, 2));
            m = fmaxf(m, __shfl_xor(m, 4));
            m = fmaxf(m, __shfl_xor(m, 8));
            mnew[r] = fmaxf(mrow[r], m);
        }
#pragma unroll
        for (int r = 0; r < 4; r++) {
            float alpha = __expf(mrow[r] - mnew[r]);
            float ssum = 0.f;
#pragma unroll
            for (int nt = 0; nt < 4; nt++) {
                float p = __expf(sc[nt][r] - mnew[r]);
                sc[nt][r] = p;
                ssum += p;
            }
            ssum += __shfl_xor(ssum, 1);
            ssum += __shfl_xor(ssum, 2);
            ssum += __shfl_xor(ssum, 4);
            ssum += __shfl_xor(ssum, 8);
            lrow[r] = lrow[r] * alpha + ssum;
            mrow[r] = mnew[r];
#pragma unroll
            for (int nt = 0; nt < 4; nt++) accO[nt][r] *= alpha;
        }

        // P (C-layout) -> LDS row-major for A-operand reads
#pragma unroll
        for (int nt = 0; nt < 4; nt++)
#pragma unroll
            for (int r = 0; r < 4; r++)
                Ps[(wv * 16 + quad * 4 + r) * 72 + nt * 16 + l15] = f2bf(sc[nt][r]);
        __syncthreads();

        // O += P V
#pragma unroll
        for (int ks = 0; ks < 2; ks++) {
            bf16x8 pa = *(const bf16x8*)&Ps[(wv * 16 + l15) * 72 + ks * 32 + quad * 8];
#pragma unroll
            for (int nt = 0; nt < 4; nt++) {
                bf16x8 bv = *(const bf16x8*)&Vs[(nt * 16 + l15) * 72 + ks * 32 + quad * 8];
                accO[nt] = __builtin_amdgcn_mfma_f32_16x16x32_bf16(pa, bv, accO[nt], 0, 0, 0);
            }
        }
    }

    const int b = bh >> 4, h = bh & 15;
#pragma unroll
    for (int nt = 0; nt < 4; nt++) {
        const int d = nt * 16 + l15;
#pragma unroll
        for (int r = 0; r < 4; r++) {
            const int qg = q0 + wv * 16 + quad * 4 + r;
            float o = accO[nt][r] / fmaxf(lrow[r], 1e-20f);
            ao[((size_t)(b * SEQ + qg)) * D_MODEL + h * HDIM + d] = f2bf(o);
        }
    }
}

// ---------------------------------------------------------------------------
extern "C" void kernel_launch(void* const* d_in, const int* in_sizes, int n_in,
                              void* d_out, int out_size, void* d_ws, size_t ws_size,
                              hipStream_t stream)
{
    (void)out_size; (void)ws_size;
    // Identify inputs by unique element counts (robust to ordering surprises).
    int ix = 0, iwq = 1, iwo = 2;
    for (int i = 0; i < n_in; i++) {
        if (in_sizes[i] == 4 * SEQ * D_MODEL)          ix  = i;  // 8388608
        else if (in_sizes[i] == 3 * D_MODEL * D_MODEL) iwq = i;  // 3145728
        else if (in_sizes[i] == D_MODEL * D_MODEL)     iwo = i;  // 1048576
    }
    const float* X    = (const float*)d_in[ix];
    const float* Wqkv = (const float*)d_in[iwq];
    const float* Wout = (const float*)d_in[iwo];
    float* out = (float*)d_out;

    char* ws = (char*)d_ws;
    const size_t SZ = (size_t)BH * SEQ * HDIM * sizeof(ushort);  // 16.78 MB
    ushort* qb = (ushort*)(ws);
    ushort* kb = (ushort*)(ws + SZ);
    ushort* vt = (ushort*)(ws + 2 * SZ);
    ushort* ao = (ushort*)(ws + 3 * SZ);   // total ws use: 67.1 MB

    gemm_qkv<<<dim3(24, 64), 256, 0, stream>>>(X, Wqkv, qb, kb, vt);
    rope_k<<<dim3((BH * SEQ * 32) / 256, 2), 256, 0, stream>>>(qb, kb);
    attn_k<<<dim3(SEQ / 64, BH), 256, 0, stream>>>(qb, kb, vt, ao);
    gemm_out<<<dim3(8, 64), 256, 0, stream>>>(ao, Wout, out);
}

// Round 4
// 485.097 us; speedup vs baseline: 1.0118x; 1.0118x over previous
//
#include <hip/hip_runtime.h>
#include <hip/hip_bf16.h>
#include <stdint.h>

#define D_MODEL 1024
#define NHEAD   16
#define HDIM    64
#define SEQ     2048
#define BH      64   // 4 batches * 16 heads

typedef short bf16x8 __attribute__((ext_vector_type(8)));
typedef float f32x4  __attribute__((ext_vector_type(4)));

static __device__ __forceinline__ float bf2f(ushort u) {
    union { uint32_t i; float f; } v; v.i = ((uint32_t)u) << 16; return v.f;
}
static __device__ __forceinline__ ushort f2bf(float f) {
    __hip_bfloat16 h = __float2bfloat16(f);
    union { __hip_bfloat16 h; ushort u; } v; v.h = h; return v.u;
}
static __device__ __forceinline__ uint32_t pk2(float a, float b) {
    return (uint32_t)f2bf(a) | ((uint32_t)f2bf(b) << 16);
}
// Load 8 fp32, convert to bf16 (RNE), store 16B to LDS.
static __device__ __forceinline__ void cvt_store8(ushort* dst, const float* src) {
    float4 a = *(const float4*)src;
    float4 b = *(const float4*)(src + 4);
    uint4 o;
    o.x = pk2(a.x, a.y);
    o.y = pk2(a.z, a.w);
    o.z = pk2(b.x, b.y);
    o.w = pk2(b.z, b.w);
    *(uint4*)dst = o;
}

// ---------------------------------------------------------------------------
// GEMM1: qkv = X[8192,1024](f32) * Wqkv[3072,1024](f32)^T, bf16 MFMA compute.
// Scatter epilogue: q,k -> [bh][s][d] bf16 ; v -> transposed [bh][d][s] bf16.
// ---------------------------------------------------------------------------
__global__ __launch_bounds__(256)
void gemm_qkv(const float* __restrict__ X, const float* __restrict__ W,
              ushort* __restrict__ qb, ushort* __restrict__ kb,
              ushort* __restrict__ vt)
{
    __shared__ ushort As[128 * 72];
    __shared__ ushort Bs[128 * 72];
    const int K = 1024;
    const int m0 = blockIdx.y * 128;
    const int n0 = blockIdx.x * 128;
    const int t = threadIdx.x;
    const int lane = t & 63, wv = t >> 6;
    const int wm = (wv >> 1) * 64, wn = (wv & 1) * 64;
    const int l15 = lane & 15, quad = lane >> 4;

    f32x4 acc[4][4];
#pragma unroll
    for (int i = 0; i < 4; i++)
#pragma unroll
        for (int j = 0; j < 4; j++) acc[i][j] = (f32x4){0.f, 0.f, 0.f, 0.f};

    for (int k0 = 0; k0 < K; k0 += 64) {
        __syncthreads();
#pragma unroll
        for (int i = 0; i < 4; i++) {
            int slot = t + 256 * i;
            int r = slot >> 3, c = (slot & 7) * 8;
            cvt_store8(&As[r * 72 + c], &X[(size_t)(m0 + r) * K + k0 + c]);
            cvt_store8(&Bs[r * 72 + c], &W[(size_t)(n0 + r) * K + k0 + c]);
        }
        __syncthreads();
#pragma unroll
        for (int ks = 0; ks < 2; ks++) {
            bf16x8 af[4], bfr[4];
            const int kc = ks * 32 + quad * 8;
#pragma unroll
            for (int mi = 0; mi < 4; mi++)
                af[mi] = *(const bf16x8*)&As[(wm + mi * 16 + l15) * 72 + kc];
#pragma unroll
            for (int ni = 0; ni < 4; ni++)
                bfr[ni] = *(const bf16x8*)&Bs[(wn + ni * 16 + l15) * 72 + kc];
#pragma unroll
            for (int ni = 0; ni < 4; ni++)
#pragma unroll
                for (int mi = 0; mi < 4; mi++)
                    acc[mi][ni] = __builtin_amdgcn_mfma_f32_16x16x32_bf16(
                        af[mi], bfr[ni], acc[mi][ni], 0, 0, 0);
        }
    }

#pragma unroll
    for (int ni = 0; ni < 4; ni++) {
        const int e = n0 + wn + ni * 16 + l15;
        const int which = e >> 10;
        const int h = (e >> 6) & 15;
        const int d = e & 63;
#pragma unroll
        for (int mi = 0; mi < 4; mi++) {
            const int gm0 = m0 + wm + mi * 16 + quad * 4;
            const int b = gm0 >> 11;
            const int s0 = gm0 & 2047;
            const int bh = b * NHEAD + h;
            if (which == 2) {
                ushort4 pk;
                pk.x = f2bf(acc[mi][ni][0]); pk.y = f2bf(acc[mi][ni][1]);
                pk.z = f2bf(acc[mi][ni][2]); pk.w = f2bf(acc[mi][ni][3]);
                *(ushort4*)&vt[((size_t)bh * HDIM + d) * SEQ + s0] = pk;
            } else {
                ushort* dst = (which == 0) ? qb : kb;
#pragma unroll
                for (int r = 0; r < 4; r++)
                    dst[((size_t)bh * SEQ + s0 + r) * HDIM + d] = f2bf(acc[mi][ni][r]);
            }
        }
    }
}

// ---------------------------------------------------------------------------
// GEMM2: out(f32) = A[8192,1024](bf16) * Wout[1024,1024](f32)^T
// ---------------------------------------------------------------------------
__global__ __launch_bounds__(256)
void gemm_out(const ushort* __restrict__ A, const float* __restrict__ W,
              float* __restrict__ out)
{
    __shared__ ushort As[128 * 72];
    __shared__ ushort Bs[128 * 72];
    const int K = 1024;
    const int m0 = blockIdx.y * 128;
    const int n0 = blockIdx.x * 128;
    const int t = threadIdx.x;
    const int lane = t & 63, wv = t >> 6;
    const int wm = (wv >> 1) * 64, wn = (wv & 1) * 64;
    const int l15 = lane & 15, quad = lane >> 4;

    f32x4 acc[4][4];
#pragma unroll
    for (int i = 0; i < 4; i++)
#pragma unroll
        for (int j = 0; j < 4; j++) acc[i][j] = (f32x4){0.f, 0.f, 0.f, 0.f};

    for (int k0 = 0; k0 < K; k0 += 64) {
        __syncthreads();
#pragma unroll
        for (int i = 0; i < 4; i++) {
            int slot = t + 256 * i;
            int r = slot >> 3, c = (slot & 7) * 8;
            *(uint4*)&As[r * 72 + c] = *(const uint4*)&A[(size_t)(m0 + r) * K + k0 + c];
            cvt_store8(&Bs[r * 72 + c], &W[(size_t)(n0 + r) * K + k0 + c]);
        }
        __syncthreads();
#pragma unroll
        for (int ks = 0; ks < 2; ks++) {
            bf16x8 af[4], bfr[4];
            const int kc = ks * 32 + quad * 8;
#pragma unroll
            for (int mi = 0; mi < 4; mi++)
                af[mi] = *(const bf16x8*)&As[(wm + mi * 16 + l15) * 72 + kc];
#pragma unroll
            for (int ni = 0; ni < 4; ni++)
                bfr[ni] = *(const bf16x8*)&Bs[(wn + ni * 16 + l15) * 72 + kc];
#pragma unroll
            for (int ni = 0; ni < 4; ni++)
#pragma unroll
                for (int mi = 0; mi < 4; mi++)
                    acc[mi][ni] = __builtin_amdgcn_mfma_f32_16x16x32_bf16(
                        af[mi], bfr[ni], acc[mi][ni], 0, 0, 0);
        }
    }

#pragma unroll
    for (int ni = 0; ni < 4; ni++) {
        const int n = n0 + wn + ni * 16 + l15;
#pragma unroll
        for (int mi = 0; mi < 4; mi++) {
            const int gm0 = m0 + wm + mi * 16 + quad * 4;
#pragma unroll
            for (int r = 0; r < 4; r++)
                out[(size_t)(gm0 + r) * 1024 + n] = acc[mi][ni][r];
        }
    }
}

// ---------------------------------------------------------------------------
// RoPE in-place on bf16 q and k buffers, layout [bh][s][64]. One thread/pair.
// ---------------------------------------------------------------------------
__global__ __launch_bounds__(256)
void rope_k(ushort* __restrict__ qb, ushort* __restrict__ kb)
{
    const int idx = blockIdx.x * blockDim.x + threadIdx.x;   // BH*SEQ*32 total
    const int i  = idx & 31;
    const int s  = (idx >> 5) & 2047;
    const int bh = idx >> 16;
    ushort* buf = blockIdx.y ? kb : qb;
    const size_t off = ((size_t)bh * SEQ + s) * HDIM + 2 * i;
    uint32_t pair = *(uint32_t*)&buf[off];
    float x1 = bf2f((ushort)(pair & 0xffff));
    float x2 = bf2f((ushort)(pair >> 16));
    float freq = expf(-(float)i * (9.2103403719761836f / 32.0f));  // 10000^(-i/32)
    float ang = (float)s * freq;
    float sn, cs;
    sincosf(ang, &sn, &cs);
    float o1 = x1 * cs - x2 * sn;
    float o2 = x2 * cs + x1 * sn;
    uint32_t op = (uint32_t)f2bf(o1) | ((uint32_t)f2bf(o2) << 16);
    *(uint32_t*)&buf[off] = op;
}

// ---------------------------------------------------------------------------
// Flash attention, causal — S^T formulation.
// Block = 4 waves, q-tile 64 (wave w owns q = q0+w*16+l15, ONE q per lane).
// S^T = K*Q^T via MFMA: C rows = k (quad*4+r), cols = q (l15).
//   -> softmax reduce over k = in-lane tree + 2 shuffles (xor16, xor32);
//      m, l, alpha are per-lane scalars.
// P^T redistributed to B-operand layout in-register (16 bpermute + 8 sel),
// no LDS round trip. O accumulated transposed (d rows); PV: A=V^T, B=P^T.
// K/V staging double-buffered: ONE barrier per k-tile.
// ---------------------------------------------------------------------------
__global__ __launch_bounds__(256)
void attn_k(const ushort* __restrict__ qb, const ushort* __restrict__ kb,
            const ushort* __restrict__ vt, ushort* __restrict__ ao)
{
    __shared__ ushort Qs[64 * 72];
    __shared__ ushort Ks[2][64 * 72];
    __shared__ ushort Vs[2][64 * 72];   // V^T tile: row = d, col = k_local

    const int qt = blockIdx.x;       // 0..31
    const int bh = blockIdx.y;       // 0..63
    const int q0 = qt * 64;
    const int t = threadIdx.x;
    const int lane = t & 63, wv = t >> 6;
    const int l15 = lane & 15, quad = lane >> 4;

    // stage Q tile
#pragma unroll
    for (int i = 0; i < 2; i++) {
        int slot = t + 256 * i;
        int r = slot >> 3, c = (slot & 7) * 8;
        *(uint4*)&Qs[r * 72 + c] =
            *(const uint4*)&qb[((size_t)bh * SEQ + q0 + r) * HDIM + c];
    }

    // staging slots for K/V (2 x uint4 each per thread)
    const int sr0 = t >> 3, sc0 = (t & 7) * 8;          // slot i=0
    const int sr1 = (t + 256) >> 3, sc1 = sc0;          // slot i=1 (same col pattern)
    uint4 krg[2], vrg[2];
    {   // prefetch kt = 0
        krg[0] = *(const uint4*)&kb[((size_t)bh * SEQ + 0 + sr0) * HDIM + sc0];
        krg[1] = *(const uint4*)&kb[((size_t)bh * SEQ + 0 + sr1) * HDIM + sc1];
        vrg[0] = *(const uint4*)&vt[((size_t)bh * HDIM + sr0) * SEQ + 0 + sc0];
        vrg[1] = *(const uint4*)&vt[((size_t)bh * HDIM + sr1) * SEQ + 0 + sc1];
    }
    __syncthreads();   // Qs visible

    // Q fragments (B-operand of S^T): hoisted out of the k-loop
    bf16x8 qa[2];
#pragma unroll
    for (int ks = 0; ks < 2; ks++)
        qa[ks] = *(const bf16x8*)&Qs[(wv * 16 + l15) * 72 + ks * 32 + quad * 8];

    const int qg = q0 + wv * 16 + l15;   // this lane's q (global)
    f32x4 accO[4];                        // O^T: row d = mi*16+quad*4+r, col q = l15
#pragma unroll
    for (int i = 0; i < 4; i++) accO[i] = (f32x4){0.f, 0.f, 0.f, 0.f};
    float m = -30000.f, l = 0.f;

    for (int kt = 0; kt <= qt; kt++) {
        const int p = kt & 1;
        // write staged regs -> LDS buffer p
        *(uint4*)&Ks[p][sr0 * 72 + sc0] = krg[0];
        *(uint4*)&Ks[p][sr1 * 72 + sc1] = krg[1];
        *(uint4*)&Vs[p][sr0 * 72 + sc0] = vrg[0];
        *(uint4*)&Vs[p][sr1 * 72 + sc1] = vrg[1];
        // prefetch next k-tile
        if (kt < qt) {
            const int kn = (kt + 1) * 64;
            krg[0] = *(const uint4*)&kb[((size_t)bh * SEQ + kn + sr0) * HDIM + sc0];
            krg[1] = *(const uint4*)&kb[((size_t)bh * SEQ + kn + sr1) * HDIM + sc1];
            vrg[0] = *(const uint4*)&vt[((size_t)bh * HDIM + sr0) * SEQ + kn + sc0];
            vrg[1] = *(const uint4*)&vt[((size_t)bh * HDIM + sr1) * SEQ + kn + sc1];
        }
        __syncthreads();   // buffer p fully written; prev compute done

        // S^T = K Q^T : st[mi] rows k = k0+mi*16+quad*4+r, col q = l15
        f32x4 st[4];
#pragma unroll
        for (int mi = 0; mi < 4; mi++) st[mi] = (f32x4){0.f, 0.f, 0.f, 0.f};
#pragma unroll
        for (int ks = 0; ks < 2; ks++) {
#pragma unroll
            for (int mi = 0; mi < 4; mi++) {
                bf16x8 ka = *(const bf16x8*)&Ks[p][(mi * 16 + l15) * 72 + ks * 32 + quad * 8];
                st[mi] = __builtin_amdgcn_mfma_f32_16x16x32_bf16(ka, qa[ks], st[mi], 0, 0, 0);
            }
        }

        const int k0 = kt * 64;
        const bool diag = (kt == qt);
#pragma unroll
        for (int mi = 0; mi < 4; mi++) {
#pragma unroll
            for (int r = 0; r < 4; r++) {
                float v = st[mi][r] * 0.125f;
                if (diag) {
                    int kg = k0 + mi * 16 + quad * 4 + r;
                    if (kg > qg) v = -30000.f;
                }
                st[mi][r] = v;
            }
        }

        // online softmax: in-lane tree over 16 k values + xor16/xor32
        float mx = st[0][0];
#pragma unroll
        for (int mi = 0; mi < 4; mi++)
#pragma unroll
            for (int r = 0; r < 4; r++) mx = fmaxf(mx, st[mi][r]);
        mx = fmaxf(mx, __shfl_xor(mx, 16));
        mx = fmaxf(mx, __shfl_xor(mx, 32));
        const float mnew = fmaxf(m, mx);
        const float alpha = __expf(m - mnew);
        float ssum = 0.f;
#pragma unroll
        for (int mi = 0; mi < 4; mi++)
#pragma unroll
            for (int r = 0; r < 4; r++) {
                float pv = __expf(st[mi][r] - mnew);
                st[mi][r] = pv;
                ssum += pv;
            }
        ssum += __shfl_xor(ssum, 16);
        ssum += __shfl_xor(ssum, 32);
        l = l * alpha + ssum;
        m = mnew;
#pragma unroll
        for (int mi = 0; mi < 4; mi++)
#pragma unroll
            for (int r = 0; r < 4; r++) accO[mi][r] *= alpha;

        // pack P to bf16 pairs: pr[mi][w] = (k = k0+mi*16+quad*4+2w, +1)
        uint32_t pr[4][2];
#pragma unroll
        for (int mi = 0; mi < 4; mi++) {
            pr[mi][0] = pk2(st[mi][0], st[mi][1]);
            pr[mi][1] = pk2(st[mi][2], st[mi][3]);
        }

        // redistribute P^T into B-operand frags + PV MFMA
        // dest slot w of ks2-frag needs k-pair kk = ks2*32 + quad*8 + 2w:
        //   mi_src = ks2*2 + (quad>>1); quad_src = (quad&1)*2 + (w>>1); w_src = w&1
        const int qlo = (quad & 1) * 2;
        const bool hi = (quad >= 2);
#pragma unroll
        for (int ks2 = 0; ks2 < 2; ks2++) {
            uint32_t pb[4];
#pragma unroll
            for (int w = 0; w < 4; w++) {
                int srcLane = (qlo + (w >> 1)) * 16 + l15;
                uint32_t va = __shfl(pr[ks2 * 2 + 0][w & 1], srcLane);
                uint32_t vb = __shfl(pr[ks2 * 2 + 1][w & 1], srcLane);
                pb[w] = hi ? vb : va;
            }
            bf16x8 pfrag;
            *(uint4*)&pfrag = *(uint4*)pb;
#pragma unroll
            for (int mi = 0; mi < 4; mi++) {
                bf16x8 vfr = *(const bf16x8*)&Vs[p][(mi * 16 + l15) * 72 + ks2 * 32 + quad * 8];
                accO[mi] = __builtin_amdgcn_mfma_f32_16x16x32_bf16(vfr, pfrag, accO[mi], 0, 0, 0);
            }
        }
    }

    // epilogue: O[q][d] = accO^T / l ; lane: q = qg, d = mi*16+quad*4+r
    const int b = bh >> 4, h = bh & 15;
    const float rl = 1.0f / fmaxf(l, 1e-20f);
#pragma unroll
    for (int mi = 0; mi < 4; mi++) {
        uint2 o;
        o.x = pk2(accO[mi][0] * rl, accO[mi][1] * rl);
        o.y = pk2(accO[mi][2] * rl, accO[mi][3] * rl);
        *(uint2*)&ao[((size_t)(b * SEQ + qg)) * D_MODEL + h * HDIM + mi * 16 + quad * 4] = o;
    }
}

// ---------------------------------------------------------------------------
extern "C" void kernel_launch(void* const* d_in, const int* in_sizes, int n_in,
                              void* d_out, int out_size, void* d_ws, size_t ws_size,
                              hipStream_t stream)
{
    (void)out_size; (void)ws_size;
    int ix = 0, iwq = 1, iwo = 2;
    for (int i = 0; i < n_in; i++) {
        if (in_sizes[i] == 4 * SEQ * D_MODEL)          ix  = i;  // 8388608
        else if (in_sizes[i] == 3 * D_MODEL * D_MODEL) iwq = i;  // 3145728
        else if (in_sizes[i] == D_MODEL * D_MODEL)     iwo = i;  // 1048576
    }
    const float* X    = (const float*)d_in[ix];
    const float* Wqkv = (const float*)d_in[iwq];
    const float* Wout = (const float*)d_in[iwo];
    float* out = (float*)d_out;

    char* ws = (char*)d_ws;
    const size_t SZ = (size_t)BH * SEQ * HDIM * sizeof(ushort);  // 16.78 MB
    ushort* qb = (ushort*)(ws);
    ushort* kb = (ushort*)(ws + SZ);
    ushort* vt = (ushort*)(ws + 2 * SZ);
    ushort* ao = (ushort*)(ws + 3 * SZ);   // total ws use: 67.1 MB

    gemm_qkv<<<dim3(24, 64), 256, 0, stream>>>(X, Wqkv, qb, kb, vt);
    rope_k<<<dim3((BH * SEQ * 32) / 256, 2), 256, 0, stream>>>(qb, kb);
    attn_k<<<dim3(SEQ / 64, BH), 256, 0, stream>>>(qb, kb, vt, ao);
    gemm_out<<<dim3(8, 64), 256, 0, stream>>>(ao, Wout, out);
}